// Round 10
// baseline (253.906 us; speedup 1.0000x reference)
//
#include <hip/hip_runtime.h>
#include <math.h>

#define DD   128
#define NQKV 384
#define CAP  128    // per-node list capacity = 4 sub-segments x 32
#define SUBCAP 32
#define CSTRIDE 32  // one sub-counter per 128B line

typedef __attribute__((ext_vector_type(8))) short          bf16x8;
typedef __attribute__((ext_vector_type(8))) unsigned short ushort8;
typedef __attribute__((ext_vector_type(4))) float          f32x4;

// ---------------- bf16 helpers ----------------
__device__ __forceinline__ unsigned short f2bf(float f) {
    unsigned u = __float_as_uint(f);
    u += 0x7fffu + ((u >> 16) & 1u);       // RTNE
    return (unsigned short)(u >> 16);
}
__device__ __forceinline__ float bf2f(unsigned short h) {
    return __uint_as_float(((unsigned)h) << 16);
}
__device__ __forceinline__ float bflo(unsigned u) { return __uint_as_float(u << 16); }
__device__ __forceinline__ float bfhi(unsigned u) { return __uint_as_float(u & 0xffff0000u); }

// ---------------- prep: zero padded sub-counters + split both weight matrices -------
#define NWQ8 (NQKV * DD / 8)   // 6144
#define NWO8 (DD * DD / 8)     // 2048

__global__ void prep_kernel(const float* __restrict__ w_qkv, const float* __restrict__ w_out,
                            unsigned short* __restrict__ wq_hi, unsigned short* __restrict__ wq_lo,
                            unsigned short* __restrict__ wo_hi, unsigned short* __restrict__ wo_lo,
                            int* __restrict__ counts, int nzc4) {
    int i = blockIdx.x * blockDim.x + threadIdx.x;
    if (i < nzc4) {                        // zero padded counter array (int4)
        ((int4*)counts)[i] = make_int4(0, 0, 0, 0);
        return;
    }
    int j = i - nzc4;
    const float* srcp;
    unsigned short *hip_, *lop_;
    if (j < NWQ8)            { srcp = w_qkv + (size_t)j * 8;          hip_ = wq_hi + (size_t)j * 8;          lop_ = wq_lo + (size_t)j * 8; }
    else if (j < NWQ8+NWO8)  { int k = j - NWQ8; srcp = w_out + (size_t)k * 8; hip_ = wo_hi + (size_t)k * 8; lop_ = wo_lo + (size_t)k * 8; }
    else return;
    const float4* p = (const float4*)srcp;
    float4 a = p[0], b = p[1];
    float v[8] = {a.x, a.y, a.z, a.w, b.x, b.y, b.z, b.w};
    ushort8 vh, vl;
    #pragma unroll
    for (int t = 0; t < 8; ++t) {
        unsigned short h = f2bf(v[t]);
        vh[t] = h;
        vl[t] = f2bf(v[t] - bf2f(h));
    }
    *(ushort8*)hip_ = vh;
    *(ushort8*)lop_ = vl;
}

// ---------------- one-pass edge-list build, 4-way sub-counters per node -------------
// Sub-counter (n,j) at counts[(n*4+j)*CSTRIDE]; list slot = n*CAP + j*32 + pos.
// Contention per counter drops 4x (Poisson(16) -> 4 per sub-counter; tail 45 -> ~12).
__global__ void scatter_fixed_kernel(const int* __restrict__ src, const int* __restrict__ dst,
                                     int* __restrict__ counts, int* __restrict__ lists, int E) {
    int e = blockIdx.x * blockDim.x + threadIdx.x;
    if (e >= E) return;
    int d = dst[e];
    int s = src[e];
    int j = e & 3;
    int pos = atomicAdd(&counts[(size_t)(d * 4 + j) * CSTRIDE], 1);
    if (pos < SUBCAP) lists[(size_t)d * CAP + j * SUBCAP + pos] = s;
}

// ---------------- MFMA GEMM tiles ----------------
#define TM 128
#define TN 128
#define LDA 40   // padded LDS row stride in shorts (80 B -> 2-way bank aliasing, free)

// QKV projection (2-pass): qkv = bf16(x) @ (w_hi + w_lo)^T + bias.
// Epilogue scatters cols into packed q[N][128] fp32, k/v[N][128] bf16.
__global__ __launch_bounds__(256, 3) void qkv_gemm_kernel(
    const float* __restrict__ X,
    const unsigned short* __restrict__ Bh, const unsigned short* __restrict__ Bl,
    const float* __restrict__ bias, float* __restrict__ Cq,
    unsigned short* __restrict__ Ck, unsigned short* __restrict__ Cv, int M)
{
    __shared__ unsigned short As[TM * LDA];     // 30 KB total
    __shared__ unsigned short Bs_h[TN * LDA];
    __shared__ unsigned short Bs_l[TN * LDA];

    const int tid  = threadIdx.x;
    const int l    = tid & 63;
    const int wv   = tid >> 6;
    const int quad = l >> 4;
    const int l15  = l & 15;
    const int wm   = (wv & 1) * 64;
    const int wn   = (wv >> 1) * 64;
    const int m0   = blockIdx.x * TM;
    const int n0   = blockIdx.y * TN;

    f32x4 acc[4][4];
    #pragma unroll
    for (int i = 0; i < 4; ++i)
        #pragma unroll
        for (int j = 0; j < 4; ++j) acc[i][j] = (f32x4)0.f;

    #pragma unroll
    for (int kc = 0; kc < DD; kc += 32) {
        #pragma unroll
        for (int it = 0; it < 2; ++it) {
            int idx = tid + it * 256;       // 0..511
            int row = idx >> 2;             // 0..127
            int pc  = idx & 3;              // 8-elem piece within 32-col chunk
            int loff = row * LDA + pc * 8;
            ushort8 va = 0;
            if (m0 + row < M) {
                const float4* xp = (const float4*)(X + (size_t)(m0 + row) * DD + kc + pc * 8);
                float4 a0 = xp[0], a1 = xp[1];
                float v[8] = {a0.x,a0.y,a0.z,a0.w,a1.x,a1.y,a1.z,a1.w};
                #pragma unroll
                for (int t = 0; t < 8; ++t) va[t] = f2bf(v[t]);
            }
            *(ushort8*)&As[loff] = va;
            size_t gb = (size_t)(n0 + row) * DD + kc + pc * 8;
            *(ushort8*)&Bs_h[loff] = *(const ushort8*)(Bh + gb);
            *(ushort8*)&Bs_l[loff] = *(const ushort8*)(Bl + gb);
        }
        __syncthreads();

        bf16x8 ah[4], bh[4], bl[4];
        #pragma unroll
        for (int mt = 0; mt < 4; ++mt)
            ah[mt] = *(const bf16x8*)&As[(wm + mt * 16 + l15) * LDA + quad * 8];
        #pragma unroll
        for (int nt = 0; nt < 4; ++nt) {
            int off = (wn + nt * 16 + l15) * LDA + quad * 8;
            bh[nt] = *(const bf16x8*)&Bs_h[off];
            bl[nt] = *(const bf16x8*)&Bs_l[off];
        }
        #pragma unroll
        for (int mt = 0; mt < 4; ++mt)
            #pragma unroll
            for (int nt = 0; nt < 4; ++nt) {
                acc[mt][nt] = __builtin_amdgcn_mfma_f32_16x16x32_bf16(ah[mt], bh[nt], acc[mt][nt], 0, 0, 0);
                acc[mt][nt] = __builtin_amdgcn_mfma_f32_16x16x32_bf16(ah[mt], bl[nt], acc[mt][nt], 0, 0, 0);
            }
        __syncthreads();
    }

    // epilogue: C/D layout col=l15, row=quad*4+rr; scatter into packed q/k/v
    #pragma unroll
    for (int nt = 0; nt < 4; ++nt) {
        int j = n0 + wn + nt * 16 + l15;
        float bj = bias[j];
        int h = j / 48;
        int r = j - h * 48;
        int seg = (r >= 32) ? 2 : ((r >= 16) ? 1 : 0);
        int bc  = h * 16 + r - seg * 16;
        #pragma unroll
        for (int mt = 0; mt < 4; ++mt)
            #pragma unroll
            for (int rr = 0; rr < 4; ++rr) {
                int m = m0 + wm + mt * 16 + quad * 4 + rr;
                if (m >= M) continue;
                float val = acc[mt][nt][rr] + bj;
                if (seg == 0)      Cq[(size_t)m * DD + bc] = val;
                else if (seg == 1) Ck[(size_t)m * DD + bc] = f2bf(val);
                else               Cv[(size_t)m * DD + bc] = f2bf(val);
            }
    }
}

// Out projection (2-pass): out = bf16(agg) @ (w_hi + w_lo)^T + bias.
// agg is already bf16 (A-quant error ~2e-3 through the 128-dot; margin holds).
__global__ __launch_bounds__(256, 3) void out_gemm_kernel(
    const unsigned short* __restrict__ A,
    const unsigned short* __restrict__ Bh, const unsigned short* __restrict__ Bl,
    const float* __restrict__ bias, float* __restrict__ C, int M)
{
    __shared__ unsigned short As[TM * LDA];
    __shared__ unsigned short Bs_h[TN * LDA];
    __shared__ unsigned short Bs_l[TN * LDA];

    const int tid  = threadIdx.x;
    const int l    = tid & 63;
    const int wv   = tid >> 6;
    const int quad = l >> 4;
    const int l15  = l & 15;
    const int wm   = (wv & 1) * 64;
    const int wn   = (wv >> 1) * 64;
    const int m0   = blockIdx.x * TM;

    f32x4 acc[4][4];
    #pragma unroll
    for (int i = 0; i < 4; ++i)
        #pragma unroll
        for (int j = 0; j < 4; ++j) acc[i][j] = (f32x4)0.f;

    #pragma unroll
    for (int kc = 0; kc < DD; kc += 32) {
        #pragma unroll
        for (int it = 0; it < 2; ++it) {
            int idx = tid + it * 256;
            int row = idx >> 2;
            int pc  = idx & 3;
            int loff = row * LDA + pc * 8;
            ushort8 va = 0;
            if (m0 + row < M)
                va = *(const ushort8*)(A + (size_t)(m0 + row) * DD + kc + pc * 8);
            *(ushort8*)&As[loff] = va;
            size_t gb = (size_t)row * DD + kc + pc * 8;   // Nout == 128, one col tile
            *(ushort8*)&Bs_h[loff] = *(const ushort8*)(Bh + gb);
            *(ushort8*)&Bs_l[loff] = *(const ushort8*)(Bl + gb);
        }
        __syncthreads();

        bf16x8 ah[4], bh[4], bl[4];
        #pragma unroll
        for (int mt = 0; mt < 4; ++mt)
            ah[mt] = *(const bf16x8*)&As[(wm + mt * 16 + l15) * LDA + quad * 8];
        #pragma unroll
        for (int nt = 0; nt < 4; ++nt) {
            int off = (wn + nt * 16 + l15) * LDA + quad * 8;
            bh[nt] = *(const bf16x8*)&Bs_h[off];
            bl[nt] = *(const bf16x8*)&Bs_l[off];
        }
        #pragma unroll
        for (int mt = 0; mt < 4; ++mt)
            #pragma unroll
            for (int nt = 0; nt < 4; ++nt) {
                acc[mt][nt] = __builtin_amdgcn_mfma_f32_16x16x32_bf16(ah[mt], bh[nt], acc[mt][nt], 0, 0, 0);
                acc[mt][nt] = __builtin_amdgcn_mfma_f32_16x16x32_bf16(ah[mt], bl[nt], acc[mt][nt], 0, 0, 0);
            }
        __syncthreads();
    }

    #pragma unroll
    for (int nt = 0; nt < 4; ++nt) {
        int j = wn + nt * 16 + l15;
        float bj = bias[j];
        #pragma unroll
        for (int mt = 0; mt < 4; ++mt)
            #pragma unroll
            for (int rr = 0; rr < 4; ++rr) {
                int m = m0 + wm + mt * 16 + quad * 4 + rr;
                if (m < M) C[(size_t)m * DD + j] = acc[mt][nt][rr] + bj;
            }
    }
}

// ---------------- wave-per-node fused attention (no-max softmax, pipelined) --------
// One 64-lane wave per node. 8 edges/chunk: head = lane>>3, edge = lane&7.
// Node's edges live in 4 sub-segments of 32 (j*32+off); logical index i maps via
// 3 compares against the sub-count prefix. Scores bounded -> p = exp(s) (no max),
// l deferred to one end-of-loop butterfly. Per-chunk serial chain:
// k-load -> dot -> exp -> bcast -> fma; next csr + 8 v rows issued up front.
__global__ __launch_bounds__(256) void wave_attn_kernel(
    const float* __restrict__ q, const unsigned short* __restrict__ kbf,
    const unsigned short* __restrict__ vbf, const int* __restrict__ lists,
    const int* __restrict__ counts,
    unsigned short* __restrict__ agg, int N)
{
    const int lane = threadIdx.x & 63;
    const int n = blockIdx.x * 4 + (threadIdx.x >> 6);
    if (n >= N) return;

    const int h = lane >> 3;      // head
    const int e = lane & 7;       // edge slot within chunk

    const int c0 = min(counts[(size_t)(n * 4 + 0) * CSTRIDE], SUBCAP);
    const int c1 = min(counts[(size_t)(n * 4 + 1) * CSTRIDE], SUBCAP);
    const int c2 = min(counts[(size_t)(n * 4 + 2) * CSTRIDE], SUBCAP);
    const int c3 = min(counts[(size_t)(n * 4 + 3) * CSTRIDE], SUBCAP);
    const int p1 = c0, p2 = c0 + c1, p3 = c0 + c1 + c2;
    const int deg = p3 + c3;

    const size_t obase = (size_t)n * DD + 2 * lane;
    if (deg == 0) {               // empty segment -> zeros (matches reference)
        *(unsigned*)(agg + obase) = 0u;
        return;
    }

    const int row0 = n * CAP;
    const float4* qp = (const float4*)(q + (size_t)n * DD + h * 16);
    const float4 q0 = qp[0], q1 = qp[1], q2 = qp[2], q3 = qp[3];

    // logical edge index -> offset within node's CAP region (segment j*32 + off)
    #define MAPI(i, res) { int _i = (i);                                   \
        int _j = (_i >= p1) + (_i >= p2) + (_i >= p3);                     \
        int _s = (_j == 0) ? 0 : ((_j == 1) ? p1 : ((_j == 2) ? p2 : p3)); \
        res = (_j << 5) + _i - _s; }

    float l_run = 0.f;
    float acc0 = 0.f, acc1 = 0.f;

    int mi;
    MAPI(min(e, deg - 1), mi);
    int cur = lists[row0 + mi];                 // chunk 0's edge src

    for (int c = 0; c < deg; c += 8) {
        const int cnt = min(8, deg - c);

        // -- issue phase: prefetch next csr, k row, all 8 v rows --
        MAPI(min(c + 8 + e, deg - 1), mi);
        const int nxt = lists[row0 + mi];
        const uint4* kp = (const uint4*)(kbf + (size_t)cur * DD + h * 16);
        const uint4 ka = kp[0], kb = kp[1];                 // k (32 B, this head)

        // cur identical across head groups (depends only on e) -> readlane/SGPR
        unsigned vv[8];
        #pragma unroll
        for (int ee = 0; ee < 8; ++ee) {
            const int sv = __shfl(cur, ee);                 // v_readlane -> sgpr
            vv[ee] = *(const unsigned*)(vbf + (size_t)sv * DD + 2 * lane);
        }

        // -- score (waits on k only; v still in flight) --
        float s = bflo(ka.x)*q0.x + bfhi(ka.x)*q0.y + bflo(ka.y)*q0.z + bfhi(ka.y)*q0.w
                + bflo(ka.z)*q1.x + bfhi(ka.z)*q1.y + bflo(ka.w)*q1.z + bfhi(ka.w)*q1.w
                + bflo(kb.x)*q2.x + bfhi(kb.x)*q2.y + bflo(kb.y)*q2.z + bfhi(kb.y)*q2.w
                + bflo(kb.z)*q3.x + bfhi(kb.z)*q3.y + bflo(kb.w)*q3.z + bfhi(kb.w)*q3.w;

        const float p = (e < cnt) ? __expf(s * 0.25f) : 0.f;   // 1/sqrt(16)
        l_run += p;

        // -- aggregation (vv arrived during score/exp) --
        #pragma unroll
        for (int ee = 0; ee < 8; ++ee) {
            const float pe = __shfl(p, (lane & 0x38) | ee);    // within own head group
            acc0 = fmaf(pe, bflo(vv[ee]), acc0);
            acc1 = fmaf(pe, bfhi(vv[ee]), acc1);
        }

        cur = nxt;
    }
    #undef MAPI

    // deferred l reduction over the 8 e-lanes of each head group
    l_run += __shfl_xor(l_run, 1);
    l_run += __shfl_xor(l_run, 2);
    l_run += __shfl_xor(l_run, 4);

    const float inv = 1.f / fmaxf(l_run, 1e-30f);
    const float o0 = acc0 * inv, o1 = acc1 * inv;
    *(unsigned*)(agg + obase) = (unsigned)f2bf(o0) | ((unsigned)f2bf(o1) << 16);
}

// ---------------- launch ----------------
extern "C" void kernel_launch(void* const* d_in, const int* in_sizes, int n_in,
                              void* d_out, int out_size, void* d_ws, size_t ws_size,
                              hipStream_t stream) {
    const float* x     = (const float*)d_in[0];
    const int*   src   = (const int*)  d_in[1];
    const int*   dst   = (const int*)  d_in[2];
    const float* w_qkv = (const float*)d_in[3];
    const float* b_qkv = (const float*)d_in[4];
    const float* w_out = (const float*)d_in[5];
    const float* b_out = (const float*)d_in[6];
    float* out = (float*)d_out;

    const int N = in_sizes[0] / DD;   // 50000
    const int E = in_sizes[1];        // 800000

    typedef unsigned short u16;
    char* ws = (char*)d_ws;
    float* qf  = (float*)ws; ws += (size_t)N * DD * sizeof(float);   // 25.6 MB
    u16* kbf   = (u16*)ws;   ws += (size_t)N * DD * sizeof(u16);     // 12.8 MB
    u16* vbf   = (u16*)ws;   ws += (size_t)N * DD * sizeof(u16);
    u16* aggb  = (u16*)ws;   ws += (size_t)N * DD * sizeof(u16);
    u16* wq_hi = (u16*)ws;   ws += (size_t)NQKV * DD * sizeof(u16);
    u16* wq_lo = (u16*)ws;   ws += (size_t)NQKV * DD * sizeof(u16);
    u16* wo_hi = (u16*)ws;   ws += (size_t)DD * DD * sizeof(u16);
    u16* wo_lo = (u16*)ws;   ws += (size_t)DD * DD * sizeof(u16);
    int* counts = (int*)ws;  ws += (size_t)N * 4 * CSTRIDE * sizeof(int); // 25.6 MB padded
    int* lists  = (int*)ws;  ws += (size_t)N * CAP * sizeof(int);         // 25.6 MB

    const int nzc4 = N * 4 * CSTRIDE / 4;
    const int npb  = (nzc4 + NWQ8 + NWO8 + 255) / 256;
    const int nsb  = (E + 255) / 256;
    const int MB   = (N + TM - 1) / TM;

    // 1) prep: zero padded sub-counters + split weights
    prep_kernel<<<npb, 256, 0, stream>>>(w_qkv, w_out, wq_hi, wq_lo, wo_hi, wo_lo,
                                         counts, nzc4);
    // 2) one-pass grouped edge-list build (4-way sub-counters)
    scatter_fixed_kernel<<<nsb, 256, 0, stream>>>(src, dst, counts, lists, E);

    // 3) QKV projection (2-pass, inline bf16 conversion of x; packed q/k/v epilogue)
    qkv_gemm_kernel<<<dim3(MB, NQKV / TN), 256, 0, stream>>>(
        x, wq_hi, wq_lo, b_qkv, qf, kbf, vbf, N);

    // 4) wave-per-node attention (emits agg as bf16)
    wave_attn_kernel<<<(N + 3) / 4, 256, 0, stream>>>(
        qf, kbf, vbf, lists, counts, aggb, N);

    // 5) output projection (2-pass split-bf16 weights)
    out_gemm_kernel<<<MB, 256, 0, stream>>>(
        aggb, wo_hi, wo_lo, b_out, out, N);
}

// Round 11
// 235.816 us; speedup vs baseline: 1.0767x; 1.0767x over previous
//
#include <hip/hip_runtime.h>
#include <math.h>

#define DD   128
#define NQKV 384
#define CAP  128   // fixed edge-list capacity per node (E/N=16 avg; P(deg>128)~0)

typedef __attribute__((ext_vector_type(8))) short          bf16x8;
typedef __attribute__((ext_vector_type(8))) unsigned short ushort8;
typedef __attribute__((ext_vector_type(4))) float          f32x4;

// ---------------- bf16 helpers ----------------
__device__ __forceinline__ unsigned short f2bf(float f) {
    unsigned u = __float_as_uint(f);
    u += 0x7fffu + ((u >> 16) & 1u);       // RTNE
    return (unsigned short)(u >> 16);
}
__device__ __forceinline__ float bf2f(unsigned short h) {
    return __uint_as_float(((unsigned)h) << 16);
}
__device__ __forceinline__ float bflo(unsigned u) { return __uint_as_float(u << 16); }
__device__ __forceinline__ float bfhi(unsigned u) { return __uint_as_float(u & 0xffff0000u); }

// ---------------- prep: zero counters + split both weight matrices ----------------
#define NWQ8 (NQKV * DD / 8)   // 6144
#define NWO8 (DD * DD / 8)     // 2048

__global__ void prep_kernel(const float* __restrict__ w_qkv, const float* __restrict__ w_out,
                            unsigned short* __restrict__ wq_hi, unsigned short* __restrict__ wq_lo,
                            unsigned short* __restrict__ wo_hi, unsigned short* __restrict__ wo_lo,
                            int* __restrict__ counts, int nzc4) {
    int i = blockIdx.x * blockDim.x + threadIdx.x;
    if (i < nzc4) {                        // zero counter array (int4)
        ((int4*)counts)[i] = make_int4(0, 0, 0, 0);
        return;
    }
    int j = i - nzc4;
    const float* srcp;
    unsigned short *hip_, *lop_;
    if (j < NWQ8)            { srcp = w_qkv + (size_t)j * 8;          hip_ = wq_hi + (size_t)j * 8;          lop_ = wq_lo + (size_t)j * 8; }
    else if (j < NWQ8+NWO8)  { int k = j - NWQ8; srcp = w_out + (size_t)k * 8; hip_ = wo_hi + (size_t)k * 8; lop_ = wo_lo + (size_t)k * 8; }
    else return;
    const float4* p = (const float4*)srcp;
    float4 a = p[0], b = p[1];
    float v[8] = {a.x, a.y, a.z, a.w, b.x, b.y, b.z, b.w};
    ushort8 vh, vl;
    #pragma unroll
    for (int t = 0; t < 8; ++t) {
        unsigned short h = f2bf(v[t]);
        vh[t] = h;
        vl[t] = f2bf(v[t] - bf2f(h));
    }
    *(ushort8*)hip_ = vh;
    *(ushort8*)lop_ = vl;
}

// ---------------- one-pass edge-list build: 8 edges/thread for atomic ILP ----------
// Serial chain per thread: 1 vector-load epoch + 1 atomic-latency epoch (8
// independent atomics in flight) + stores — vs 8 full epochs at 1 edge/thread.
__global__ void scatter_fixed_kernel(const int* __restrict__ src, const int* __restrict__ dst,
                                     int* __restrict__ counts, int* __restrict__ lists, int E) {
    int t = blockIdx.x * blockDim.x + threadIdx.x;
    int base = t * 8;
    if (base >= E) return;
    if (base + 8 <= E) {
        int4 d0 = *(const int4*)(dst + base);
        int4 d1 = *(const int4*)(dst + base + 4);
        int4 s0 = *(const int4*)(src + base);
        int4 s1 = *(const int4*)(src + base + 4);
        int dd[8] = {d0.x, d0.y, d0.z, d0.w, d1.x, d1.y, d1.z, d1.w};
        int ss[8] = {s0.x, s0.y, s0.z, s0.w, s1.x, s1.y, s1.z, s1.w};
        int pos[8];
        #pragma unroll
        for (int i = 0; i < 8; ++i) pos[i] = atomicAdd(&counts[dd[i]], 1);
        #pragma unroll
        for (int i = 0; i < 8; ++i)
            if (pos[i] < CAP) lists[(size_t)dd[i] * CAP + pos[i]] = ss[i];
    } else {
        for (int e = base; e < E; ++e) {
            int d = dst[e];
            int pos = atomicAdd(&counts[d], 1);
            if (pos < CAP) lists[(size_t)d * CAP + pos] = src[e];
        }
    }
}

// ---------------- MFMA GEMM tiles ----------------
#define TM 128
#define TN 128
#define LDA 40   // padded LDS row stride in shorts (80 B -> 2-way bank aliasing, free)

// QKV projection (2-pass): qkv = bf16(x) @ (w_hi + w_lo)^T + bias.
// Epilogue scatters cols into packed q[N][128] fp32, k/v[N][128] bf16.
__global__ __launch_bounds__(256, 3) void qkv_gemm_kernel(
    const float* __restrict__ X,
    const unsigned short* __restrict__ Bh, const unsigned short* __restrict__ Bl,
    const float* __restrict__ bias, float* __restrict__ Cq,
    unsigned short* __restrict__ Ck, unsigned short* __restrict__ Cv, int M)
{
    __shared__ unsigned short As[TM * LDA];     // 30 KB total
    __shared__ unsigned short Bs_h[TN * LDA];
    __shared__ unsigned short Bs_l[TN * LDA];

    const int tid  = threadIdx.x;
    const int l    = tid & 63;
    const int wv   = tid >> 6;
    const int quad = l >> 4;
    const int l15  = l & 15;
    const int wm   = (wv & 1) * 64;
    const int wn   = (wv >> 1) * 64;
    const int m0   = blockIdx.x * TM;
    const int n0   = blockIdx.y * TN;

    f32x4 acc[4][4];
    #pragma unroll
    for (int i = 0; i < 4; ++i)
        #pragma unroll
        for (int j = 0; j < 4; ++j) acc[i][j] = (f32x4)0.f;

    #pragma unroll
    for (int kc = 0; kc < DD; kc += 32) {
        #pragma unroll
        for (int it = 0; it < 2; ++it) {
            int idx = tid + it * 256;       // 0..511
            int row = idx >> 2;             // 0..127
            int pc  = idx & 3;              // 8-elem piece within 32-col chunk
            int loff = row * LDA + pc * 8;
            ushort8 va = 0;
            if (m0 + row < M) {
                const float4* xp = (const float4*)(X + (size_t)(m0 + row) * DD + kc + pc * 8);
                float4 a0 = xp[0], a1 = xp[1];
                float v[8] = {a0.x,a0.y,a0.z,a0.w,a1.x,a1.y,a1.z,a1.w};
                #pragma unroll
                for (int t = 0; t < 8; ++t) va[t] = f2bf(v[t]);
            }
            *(ushort8*)&As[loff] = va;
            size_t gb = (size_t)(n0 + row) * DD + kc + pc * 8;
            *(ushort8*)&Bs_h[loff] = *(const ushort8*)(Bh + gb);
            *(ushort8*)&Bs_l[loff] = *(const ushort8*)(Bl + gb);
        }
        __syncthreads();

        bf16x8 ah[4], bh[4], bl[4];
        #pragma unroll
        for (int mt = 0; mt < 4; ++mt)
            ah[mt] = *(const bf16x8*)&As[(wm + mt * 16 + l15) * LDA + quad * 8];
        #pragma unroll
        for (int nt = 0; nt < 4; ++nt) {
            int off = (wn + nt * 16 + l15) * LDA + quad * 8;
            bh[nt] = *(const bf16x8*)&Bs_h[off];
            bl[nt] = *(const bf16x8*)&Bs_l[off];
        }
        #pragma unroll
        for (int mt = 0; mt < 4; ++mt)
            #pragma unroll
            for (int nt = 0; nt < 4; ++nt) {
                acc[mt][nt] = __builtin_amdgcn_mfma_f32_16x16x32_bf16(ah[mt], bh[nt], acc[mt][nt], 0, 0, 0);
                acc[mt][nt] = __builtin_amdgcn_mfma_f32_16x16x32_bf16(ah[mt], bl[nt], acc[mt][nt], 0, 0, 0);
            }
        __syncthreads();
    }

    // epilogue: C/D layout col=l15, row=quad*4+rr; scatter into packed q/k/v
    #pragma unroll
    for (int nt = 0; nt < 4; ++nt) {
        int j = n0 + wn + nt * 16 + l15;
        float bj = bias[j];
        int h = j / 48;
        int r = j - h * 48;
        int seg = (r >= 32) ? 2 : ((r >= 16) ? 1 : 0);
        int bc  = h * 16 + r - seg * 16;
        #pragma unroll
        for (int mt = 0; mt < 4; ++mt)
            #pragma unroll
            for (int rr = 0; rr < 4; ++rr) {
                int m = m0 + wm + mt * 16 + quad * 4 + rr;
                if (m >= M) continue;
                float val = acc[mt][nt][rr] + bj;
                if (seg == 0)      Cq[(size_t)m * DD + bc] = val;
                else if (seg == 1) Ck[(size_t)m * DD + bc] = f2bf(val);
                else               Cv[(size_t)m * DD + bc] = f2bf(val);
            }
    }
}

// Out projection (2-pass): out = bf16(agg) @ (w_hi + w_lo)^T + bias.
__global__ __launch_bounds__(256, 3) void out_gemm_kernel(
    const unsigned short* __restrict__ A,
    const unsigned short* __restrict__ Bh, const unsigned short* __restrict__ Bl,
    const float* __restrict__ bias, float* __restrict__ C, int M)
{
    __shared__ unsigned short As[TM * LDA];
    __shared__ unsigned short Bs_h[TN * LDA];
    __shared__ unsigned short Bs_l[TN * LDA];

    const int tid  = threadIdx.x;
    const int l    = tid & 63;
    const int wv   = tid >> 6;
    const int quad = l >> 4;
    const int l15  = l & 15;
    const int wm   = (wv & 1) * 64;
    const int wn   = (wv >> 1) * 64;
    const int m0   = blockIdx.x * TM;

    f32x4 acc[4][4];
    #pragma unroll
    for (int i = 0; i < 4; ++i)
        #pragma unroll
        for (int j = 0; j < 4; ++j) acc[i][j] = (f32x4)0.f;

    #pragma unroll
    for (int kc = 0; kc < DD; kc += 32) {
        #pragma unroll
        for (int it = 0; it < 2; ++it) {
            int idx = tid + it * 256;
            int row = idx >> 2;
            int pc  = idx & 3;
            int loff = row * LDA + pc * 8;
            ushort8 va = 0;
            if (m0 + row < M)
                va = *(const ushort8*)(A + (size_t)(m0 + row) * DD + kc + pc * 8);
            *(ushort8*)&As[loff] = va;
            size_t gb = (size_t)row * DD + kc + pc * 8;   // Nout == 128, one col tile
            *(ushort8*)&Bs_h[loff] = *(const ushort8*)(Bh + gb);
            *(ushort8*)&Bs_l[loff] = *(const ushort8*)(Bl + gb);
        }
        __syncthreads();

        bf16x8 ah[4], bh[4], bl[4];
        #pragma unroll
        for (int mt = 0; mt < 4; ++mt)
            ah[mt] = *(const bf16x8*)&As[(wm + mt * 16 + l15) * LDA + quad * 8];
        #pragma unroll
        for (int nt = 0; nt < 4; ++nt) {
            int off = (wn + nt * 16 + l15) * LDA + quad * 8;
            bh[nt] = *(const bf16x8*)&Bs_h[off];
            bl[nt] = *(const bf16x8*)&Bs_l[off];
        }
        #pragma unroll
        for (int mt = 0; mt < 4; ++mt)
            #pragma unroll
            for (int nt = 0; nt < 4; ++nt) {
                acc[mt][nt] = __builtin_amdgcn_mfma_f32_16x16x32_bf16(ah[mt], bh[nt], acc[mt][nt], 0, 0, 0);
                acc[mt][nt] = __builtin_amdgcn_mfma_f32_16x16x32_bf16(ah[mt], bl[nt], acc[mt][nt], 0, 0, 0);
            }
        __syncthreads();
    }

    #pragma unroll
    for (int nt = 0; nt < 4; ++nt) {
        int j = wn + nt * 16 + l15;
        float bj = bias[j];
        #pragma unroll
        for (int mt = 0; mt < 4; ++mt)
            #pragma unroll
            for (int rr = 0; rr < 4; ++rr) {
                int m = m0 + wm + mt * 16 + quad * 4 + rr;
                if (m < M) C[(size_t)m * DD + j] = acc[mt][nt][rr] + bj;
            }
    }
}

// ---------------- wave-per-node fused attention (no-max softmax, pipelined) --------
// One 64-lane wave per node. 8 edges/chunk: head = lane>>3, edge = lane&7.
// Scores bounded (|s| << 88) -> p = exp(s) (no running max), l deferred to one
// end-of-loop butterfly. Per-chunk serial chain: k-load -> dot -> exp -> bcast -> fma;
// next list entry + 8 v rows issued up front. cur depends only on lane&7 ->
// __shfl(cur, literal) lowers to readlane/SGPR-base addressing.
__global__ __launch_bounds__(256) void wave_attn_kernel(
    const float* __restrict__ q, const unsigned short* __restrict__ kbf,
    const unsigned short* __restrict__ vbf, const int* __restrict__ lists,
    const int* __restrict__ counts,
    unsigned short* __restrict__ agg, int N)
{
    const int lane = threadIdx.x & 63;
    const int n = blockIdx.x * 4 + (threadIdx.x >> 6);
    if (n >= N) return;

    const int h = lane >> 3;      // head
    const int e = lane & 7;       // edge slot within chunk

    const int deg = min(counts[n], CAP);
    const size_t obase = (size_t)n * DD + 2 * lane;
    if (deg == 0) {               // empty segment -> zeros (matches reference)
        *(unsigned*)(agg + obase) = 0u;
        return;
    }

    const int row0 = n * CAP;
    const float4* qp = (const float4*)(q + (size_t)n * DD + h * 16);
    const float4 q0 = qp[0], q1 = qp[1], q2 = qp[2], q3 = qp[3];

    float l_run = 0.f;
    float acc0 = 0.f, acc1 = 0.f;

    int cur = lists[row0 + min(e, deg - 1)];     // chunk 0's edge src

    for (int c = 0; c < deg; c += 8) {
        const int cnt = min(8, deg - c);

        // -- issue phase: prefetch next list entry, k row, all 8 v rows --
        const int nxt = lists[row0 + min(c + 8 + e, deg - 1)];
        const uint4* kp = (const uint4*)(kbf + (size_t)cur * DD + h * 16);
        const uint4 ka = kp[0], kb = kp[1];                 // k (32 B, this head)

        // cur identical across head groups (depends only on e) -> readlane/SGPR
        unsigned vv[8];
        #pragma unroll
        for (int ee = 0; ee < 8; ++ee) {
            const int sv = __shfl(cur, ee);                 // v_readlane -> sgpr
            vv[ee] = *(const unsigned*)(vbf + (size_t)sv * DD + 2 * lane);
        }

        // -- score (waits on k only; v still in flight) --
        float s = bflo(ka.x)*q0.x + bfhi(ka.x)*q0.y + bflo(ka.y)*q0.z + bfhi(ka.y)*q0.w
                + bflo(ka.z)*q1.x + bfhi(ka.z)*q1.y + bflo(ka.w)*q1.z + bfhi(ka.w)*q1.w
                + bflo(kb.x)*q2.x + bfhi(kb.x)*q2.y + bflo(kb.y)*q2.z + bfhi(kb.y)*q2.w
                + bflo(kb.z)*q3.x + bfhi(kb.z)*q3.y + bflo(kb.w)*q3.z + bfhi(kb.w)*q3.w;

        const float p = (e < cnt) ? __expf(s * 0.25f) : 0.f;   // 1/sqrt(16)
        l_run += p;

        // -- aggregation (vv arrived during score/exp) --
        #pragma unroll
        for (int ee = 0; ee < 8; ++ee) {
            const float pe = __shfl(p, (lane & 0x38) | ee);    // within own head group
            acc0 = fmaf(pe, bflo(vv[ee]), acc0);
            acc1 = fmaf(pe, bfhi(vv[ee]), acc1);
        }

        cur = nxt;
    }

    // deferred l reduction over the 8 e-lanes of each head group
    l_run += __shfl_xor(l_run, 1);
    l_run += __shfl_xor(l_run, 2);
    l_run += __shfl_xor(l_run, 4);

    const float inv = 1.f / fmaxf(l_run, 1e-30f);
    const float o0 = acc0 * inv, o1 = acc1 * inv;
    *(unsigned*)(agg + obase) = (unsigned)f2bf(o0) | ((unsigned)f2bf(o1) << 16);
}

// ---------------- launch ----------------
extern "C" void kernel_launch(void* const* d_in, const int* in_sizes, int n_in,
                              void* d_out, int out_size, void* d_ws, size_t ws_size,
                              hipStream_t stream) {
    const float* x     = (const float*)d_in[0];
    const int*   src   = (const int*)  d_in[1];
    const int*   dst   = (const int*)  d_in[2];
    const float* w_qkv = (const float*)d_in[3];
    const float* b_qkv = (const float*)d_in[4];
    const float* w_out = (const float*)d_in[5];
    const float* b_out = (const float*)d_in[6];
    float* out = (float*)d_out;

    const int N = in_sizes[0] / DD;   // 50000
    const int E = in_sizes[1];        // 800000

    typedef unsigned short u16;
    char* ws = (char*)d_ws;
    float* qf  = (float*)ws; ws += (size_t)N * DD * sizeof(float);   // 25.6 MB
    u16* kbf   = (u16*)ws;   ws += (size_t)N * DD * sizeof(u16);     // 12.8 MB
    u16* vbf   = (u16*)ws;   ws += (size_t)N * DD * sizeof(u16);
    u16* aggb  = (u16*)ws;   ws += (size_t)N * DD * sizeof(u16);
    u16* wq_hi = (u16*)ws;   ws += (size_t)NQKV * DD * sizeof(u16);
    u16* wq_lo = (u16*)ws;   ws += (size_t)NQKV * DD * sizeof(u16);
    u16* wo_hi = (u16*)ws;   ws += (size_t)DD * DD * sizeof(u16);
    u16* wo_lo = (u16*)ws;   ws += (size_t)DD * DD * sizeof(u16);
    int* counts = (int*)ws;  ws += (size_t)((N + 3) / 4 * 4) * sizeof(int); // 200 KB
    int* lists  = (int*)ws;  ws += (size_t)N * CAP * sizeof(int);           // 25.6 MB

    const int nzc4 = (N + 3) / 4;
    const int npb  = (nzc4 + NWQ8 + NWO8 + 255) / 256;
    const int nsb  = ((E + 7) / 8 + 255) / 256;   // 8 edges/thread
    const int MB   = (N + TM - 1) / TM;

    // 1) prep: zero counters + split weights
    prep_kernel<<<npb, 256, 0, stream>>>(w_qkv, w_out, wq_hi, wq_lo, wo_hi, wo_lo,
                                         counts, nzc4);
    // 2) one-pass grouped edge-list build (8 edges/thread, atomic ILP)
    scatter_fixed_kernel<<<nsb, 256, 0, stream>>>(src, dst, counts, lists, E);

    // 3) QKV projection (2-pass, inline bf16 conversion of x; packed q/k/v epilogue)
    qkv_gemm_kernel<<<dim3(MB, NQKV / TN), 256, 0, stream>>>(
        x, wq_hi, wq_lo, b_qkv, qf, kbf, vbf, N);

    // 4) wave-per-node attention (emits agg as bf16)
    wave_attn_kernel<<<(N + 3) / 4, 256, 0, stream>>>(
        qf, kbf, vbf, lists, counts, aggb, N);

    // 5) output projection (2-pass split-bf16 weights)
    out_gemm_kernel<<<MB, 256, 0, stream>>>(
        aggb, wo_hi, wo_lo, b_out, out, N);
}

// Round 12
// 235.381 us; speedup vs baseline: 1.0787x; 1.0018x over previous
//
#include <hip/hip_runtime.h>
#include <math.h>

#define DD   128
#define NQKV 384
#define CAP  128   // fixed edge-list capacity per node (E/N=16 avg; P(deg>128)~0)

typedef __attribute__((ext_vector_type(8))) short          bf16x8;
typedef __attribute__((ext_vector_type(8))) unsigned short ushort8;
typedef __attribute__((ext_vector_type(4))) float          f32x4;

// ---------------- bf16 helpers ----------------
__device__ __forceinline__ unsigned short f2bf(float f) {
    unsigned u = __float_as_uint(f);
    u += 0x7fffu + ((u >> 16) & 1u);       // RTNE
    return (unsigned short)(u >> 16);
}
__device__ __forceinline__ float bf2f(unsigned short h) {
    return __uint_as_float(((unsigned)h) << 16);
}
__device__ __forceinline__ float bflo(unsigned u) { return __uint_as_float(u << 16); }
__device__ __forceinline__ float bfhi(unsigned u) { return __uint_as_float(u & 0xffff0000u); }

// ---------------- prep: zero counters + split both weight matrices ----------------
#define NWQ8 (NQKV * DD / 8)   // 6144
#define NWO8 (DD * DD / 8)     // 2048

__global__ void prep_kernel(const float* __restrict__ w_qkv, const float* __restrict__ w_out,
                            unsigned short* __restrict__ wq_hi, unsigned short* __restrict__ wq_lo,
                            unsigned short* __restrict__ wo_hi, unsigned short* __restrict__ wo_lo,
                            int* __restrict__ counts, int nzc4) {
    int i = blockIdx.x * blockDim.x + threadIdx.x;
    if (i < nzc4) {                        // zero counter array (int4)
        ((int4*)counts)[i] = make_int4(0, 0, 0, 0);
        return;
    }
    int j = i - nzc4;
    const float* srcp;
    unsigned short *hip_, *lop_;
    if (j < NWQ8)            { srcp = w_qkv + (size_t)j * 8;          hip_ = wq_hi + (size_t)j * 8;          lop_ = wq_lo + (size_t)j * 8; }
    else if (j < NWQ8+NWO8)  { int k = j - NWQ8; srcp = w_out + (size_t)k * 8; hip_ = wo_hi + (size_t)k * 8; lop_ = wo_lo + (size_t)k * 8; }
    else return;
    const float4* p = (const float4*)srcp;
    float4 a = p[0], b = p[1];
    float v[8] = {a.x, a.y, a.z, a.w, b.x, b.y, b.z, b.w};
    ushort8 vh, vl;
    #pragma unroll
    for (int t = 0; t < 8; ++t) {
        unsigned short h = f2bf(v[t]);
        vh[t] = h;
        vl[t] = f2bf(v[t] - bf2f(h));
    }
    *(ushort8*)hip_ = vh;
    *(ushort8*)lop_ = vl;
}

// ---------------- one-pass edge-list build: 8 edges/thread for atomic ILP ----------
__global__ void scatter_fixed_kernel(const int* __restrict__ src, const int* __restrict__ dst,
                                     int* __restrict__ counts, int* __restrict__ lists, int E) {
    int t = blockIdx.x * blockDim.x + threadIdx.x;
    int base = t * 8;
    if (base >= E) return;
    if (base + 8 <= E) {
        int4 d0 = *(const int4*)(dst + base);
        int4 d1 = *(const int4*)(dst + base + 4);
        int4 s0 = *(const int4*)(src + base);
        int4 s1 = *(const int4*)(src + base + 4);
        int dd[8] = {d0.x, d0.y, d0.z, d0.w, d1.x, d1.y, d1.z, d1.w};
        int ss[8] = {s0.x, s0.y, s0.z, s0.w, s1.x, s1.y, s1.z, s1.w};
        int pos[8];
        #pragma unroll
        for (int i = 0; i < 8; ++i) pos[i] = atomicAdd(&counts[dd[i]], 1);
        #pragma unroll
        for (int i = 0; i < 8; ++i)
            if (pos[i] < CAP) lists[(size_t)dd[i] * CAP + pos[i]] = ss[i];
    } else {
        for (int e = base; e < E; ++e) {
            int d = dst[e];
            int pos = atomicAdd(&counts[d], 1);
            if (pos < CAP) lists[(size_t)d * CAP + pos] = src[e];
        }
    }
}

// ---------------- MFMA GEMM tiles ----------------
#define TM 128
#define TN 128
#define LDA 40   // padded LDS row stride in shorts (80 B -> 2-way bank aliasing, free)

// QKV projection (2-pass): qkv = bf16(x) @ (w_hi + w_lo)^T + bias.
// Epilogue scatters cols into packed q/k/v [N][128], all bf16.
// Grid: (n-tiles, m-tiles) — n fastest, so the 3 col-tiles sharing an x m-tile
// are adjacent in dispatch order (L2/L3 temporal reuse of x).
__global__ __launch_bounds__(256, 3) void qkv_gemm_kernel(
    const float* __restrict__ X,
    const unsigned short* __restrict__ Bh, const unsigned short* __restrict__ Bl,
    const float* __restrict__ bias, unsigned short* __restrict__ Cq,
    unsigned short* __restrict__ Ck, unsigned short* __restrict__ Cv, int M)
{
    __shared__ unsigned short As[TM * LDA];     // 30 KB total
    __shared__ unsigned short Bs_h[TN * LDA];
    __shared__ unsigned short Bs_l[TN * LDA];

    const int tid  = threadIdx.x;
    const int l    = tid & 63;
    const int wv   = tid >> 6;
    const int quad = l >> 4;
    const int l15  = l & 15;
    const int wm   = (wv & 1) * 64;
    const int wn   = (wv >> 1) * 64;
    const int n0   = blockIdx.x * TN;
    const int m0   = blockIdx.y * TM;

    f32x4 acc[4][4];
    #pragma unroll
    for (int i = 0; i < 4; ++i)
        #pragma unroll
        for (int j = 0; j < 4; ++j) acc[i][j] = (f32x4)0.f;

    #pragma unroll
    for (int kc = 0; kc < DD; kc += 32) {
        #pragma unroll
        for (int it = 0; it < 2; ++it) {
            int idx = tid + it * 256;       // 0..511
            int row = idx >> 2;             // 0..127
            int pc  = idx & 3;              // 8-elem piece within 32-col chunk
            int loff = row * LDA + pc * 8;
            ushort8 va = 0;
            if (m0 + row < M) {
                const float4* xp = (const float4*)(X + (size_t)(m0 + row) * DD + kc + pc * 8);
                float4 a0 = xp[0], a1 = xp[1];
                float v[8] = {a0.x,a0.y,a0.z,a0.w,a1.x,a1.y,a1.z,a1.w};
                #pragma unroll
                for (int t = 0; t < 8; ++t) va[t] = f2bf(v[t]);
            }
            *(ushort8*)&As[loff] = va;
            size_t gb = (size_t)(n0 + row) * DD + kc + pc * 8;
            *(ushort8*)&Bs_h[loff] = *(const ushort8*)(Bh + gb);
            *(ushort8*)&Bs_l[loff] = *(const ushort8*)(Bl + gb);
        }
        __syncthreads();

        bf16x8 ah[4], bh[4], bl[4];
        #pragma unroll
        for (int mt = 0; mt < 4; ++mt)
            ah[mt] = *(const bf16x8*)&As[(wm + mt * 16 + l15) * LDA + quad * 8];
        #pragma unroll
        for (int nt = 0; nt < 4; ++nt) {
            int off = (wn + nt * 16 + l15) * LDA + quad * 8;
            bh[nt] = *(const bf16x8*)&Bs_h[off];
            bl[nt] = *(const bf16x8*)&Bs_l[off];
        }
        #pragma unroll
        for (int mt = 0; mt < 4; ++mt)
            #pragma unroll
            for (int nt = 0; nt < 4; ++nt) {
                acc[mt][nt] = __builtin_amdgcn_mfma_f32_16x16x32_bf16(ah[mt], bh[nt], acc[mt][nt], 0, 0, 0);
                acc[mt][nt] = __builtin_amdgcn_mfma_f32_16x16x32_bf16(ah[mt], bl[nt], acc[mt][nt], 0, 0, 0);
            }
        __syncthreads();
    }

    // epilogue: C/D layout col=l15, row=quad*4+rr; scatter into packed q/k/v (bf16)
    #pragma unroll
    for (int nt = 0; nt < 4; ++nt) {
        int j = n0 + wn + nt * 16 + l15;
        float bj = bias[j];
        int h = j / 48;
        int r = j - h * 48;
        int seg = (r >= 32) ? 2 : ((r >= 16) ? 1 : 0);
        int bc  = h * 16 + r - seg * 16;
        unsigned short* dstp = (seg == 0 ? Cq : (seg == 1 ? Ck : Cv));
        #pragma unroll
        for (int mt = 0; mt < 4; ++mt)
            #pragma unroll
            for (int rr = 0; rr < 4; ++rr) {
                int m = m0 + wm + mt * 16 + quad * 4 + rr;
                if (m < M) dstp[(size_t)m * DD + bc] = f2bf(acc[mt][nt][rr] + bj);
            }
    }
}

// Out projection (2-pass): out = bf16(agg) @ (w_hi + w_lo)^T + bias.
__global__ __launch_bounds__(256, 3) void out_gemm_kernel(
    const unsigned short* __restrict__ A,
    const unsigned short* __restrict__ Bh, const unsigned short* __restrict__ Bl,
    const float* __restrict__ bias, float* __restrict__ C, int M)
{
    __shared__ unsigned short As[TM * LDA];
    __shared__ unsigned short Bs_h[TN * LDA];
    __shared__ unsigned short Bs_l[TN * LDA];

    const int tid  = threadIdx.x;
    const int l    = tid & 63;
    const int wv   = tid >> 6;
    const int quad = l >> 4;
    const int l15  = l & 15;
    const int wm   = (wv & 1) * 64;
    const int wn   = (wv >> 1) * 64;
    const int m0   = blockIdx.x * TM;

    f32x4 acc[4][4];
    #pragma unroll
    for (int i = 0; i < 4; ++i)
        #pragma unroll
        for (int j = 0; j < 4; ++j) acc[i][j] = (f32x4)0.f;

    #pragma unroll
    for (int kc = 0; kc < DD; kc += 32) {
        #pragma unroll
        for (int it = 0; it < 2; ++it) {
            int idx = tid + it * 256;
            int row = idx >> 2;
            int pc  = idx & 3;
            int loff = row * LDA + pc * 8;
            ushort8 va = 0;
            if (m0 + row < M)
                va = *(const ushort8*)(A + (size_t)(m0 + row) * DD + kc + pc * 8);
            *(ushort8*)&As[loff] = va;
            size_t gb = (size_t)row * DD + kc + pc * 8;   // Nout == 128, one col tile
            *(ushort8*)&Bs_h[loff] = *(const ushort8*)(Bh + gb);
            *(ushort8*)&Bs_l[loff] = *(const ushort8*)(Bl + gb);
        }
        __syncthreads();

        bf16x8 ah[4], bh[4], bl[4];
        #pragma unroll
        for (int mt = 0; mt < 4; ++mt)
            ah[mt] = *(const bf16x8*)&As[(wm + mt * 16 + l15) * LDA + quad * 8];
        #pragma unroll
        for (int nt = 0; nt < 4; ++nt) {
            int off = (wn + nt * 16 + l15) * LDA + quad * 8;
            bh[nt] = *(const bf16x8*)&Bs_h[off];
            bl[nt] = *(const bf16x8*)&Bs_l[off];
        }
        #pragma unroll
        for (int mt = 0; mt < 4; ++mt)
            #pragma unroll
            for (int nt = 0; nt < 4; ++nt) {
                acc[mt][nt] = __builtin_amdgcn_mfma_f32_16x16x32_bf16(ah[mt], bh[nt], acc[mt][nt], 0, 0, 0);
                acc[mt][nt] = __builtin_amdgcn_mfma_f32_16x16x32_bf16(ah[mt], bl[nt], acc[mt][nt], 0, 0, 0);
            }
        __syncthreads();
    }

    #pragma unroll
    for (int nt = 0; nt < 4; ++nt) {
        int j = wn + nt * 16 + l15;
        float bj = bias[j];
        #pragma unroll
        for (int mt = 0; mt < 4; ++mt)
            #pragma unroll
            for (int rr = 0; rr < 4; ++rr) {
                int m = m0 + wm + mt * 16 + quad * 4 + rr;
                if (m < M) C[(size_t)m * DD + j] = acc[mt][nt][rr] + bj;
            }
    }
}

// ---------------- wave-per-node fused attention (software-pipelined) ----------------
// One 64-lane wave per node. 8 edges/chunk: head = lane>>3, edge = lane&7.
// Pipeline: iteration c issues chunk (c+8)'s k/v loads (addresses from `nxt`,
// loaded two iterations back) BEFORE consuming chunk c's already-arrived k/v.
// Per-iter serial chain is pure VALU; gathers overlap compute. No-max softmax
// (scores bounded), l deferred to one end butterfly. q/k/v all bf16.
__global__ __launch_bounds__(256) void wave_attn_kernel(
    const unsigned short* __restrict__ qbf, const unsigned short* __restrict__ kbf,
    const unsigned short* __restrict__ vbf, const int* __restrict__ lists,
    const int* __restrict__ counts,
    unsigned short* __restrict__ agg, int N)
{
    const int lane = threadIdx.x & 63;
    const int n = blockIdx.x * 4 + (threadIdx.x >> 6);
    if (n >= N) return;

    const int h = lane >> 3;      // head
    const int e = lane & 7;       // edge slot within chunk

    const int deg = min(counts[n], CAP);
    const size_t obase = (size_t)n * DD + 2 * lane;
    if (deg == 0) {               // empty segment -> zeros (matches reference)
        *(unsigned*)(agg + obase) = 0u;
        return;
    }

    const int row0 = n * CAP;

    // q (bf16, 16 elems for this head) -> fp32 registers
    const uint4* qp = (const uint4*)(qbf + (size_t)n * DD + h * 16);
    const uint4 qa = qp[0], qb = qp[1];
    const float4 q0 = make_float4(bflo(qa.x), bfhi(qa.x), bflo(qa.y), bfhi(qa.y));
    const float4 q1 = make_float4(bflo(qa.z), bfhi(qa.z), bflo(qa.w), bfhi(qa.w));
    const float4 q2 = make_float4(bflo(qb.x), bfhi(qb.x), bflo(qb.y), bfhi(qb.y));
    const float4 q3 = make_float4(bflo(qb.z), bfhi(qb.z), bflo(qb.w), bfhi(qb.w));

    int cur = lists[row0 + min(e, deg - 1)];          // chunk 0 srcs
    int nxt = lists[row0 + min(8 + e, deg - 1)];      // chunk 1 srcs

    // prologue: issue chunk 0's k + v loads
    const uint4* kp0 = (const uint4*)(kbf + (size_t)cur * DD + h * 16);
    uint4 ka = kp0[0], kb = kp0[1];
    unsigned vv[8];
    #pragma unroll
    for (int ee = 0; ee < 8; ++ee)
        vv[ee] = *(const unsigned*)(vbf + (size_t)__shfl(cur, ee) * DD + 2 * lane);

    float l_run = 0.f;
    float acc0 = 0.f, acc1 = 0.f;

    for (int c = 0; c < deg; c += 8) {
        const int cnt = min(8, deg - c);
        const bool more = (c + 8 < deg);              // wave-uniform

        // -- lists prefetch (two chunks ahead) --
        const int nn = lists[row0 + min(c + 16 + e, deg - 1)];

        // -- issue next chunk's k/v (addresses ready in nxt) --
        uint4 k1a = ka, k1b = kb;
        unsigned vn[8];
        #pragma unroll
        for (int ee = 0; ee < 8; ++ee) vn[ee] = vv[ee];
        if (more) {
            const uint4* kp = (const uint4*)(kbf + (size_t)nxt * DD + h * 16);
            k1a = kp[0]; k1b = kp[1];
            #pragma unroll
            for (int ee = 0; ee < 8; ++ee)
                vn[ee] = *(const unsigned*)(vbf + (size_t)__shfl(nxt, ee) * DD + 2 * lane);
        }

        // -- consume current chunk (k/vv arrived during previous iteration) --
        float s = bflo(ka.x)*q0.x + bfhi(ka.x)*q0.y + bflo(ka.y)*q0.z + bfhi(ka.y)*q0.w
                + bflo(ka.z)*q1.x + bfhi(ka.z)*q1.y + bflo(ka.w)*q1.z + bfhi(ka.w)*q1.w
                + bflo(kb.x)*q2.x + bfhi(kb.x)*q2.y + bflo(kb.y)*q2.z + bfhi(kb.y)*q2.w
                + bflo(kb.z)*q3.x + bfhi(kb.z)*q3.y + bflo(kb.w)*q3.z + bfhi(kb.w)*q3.w;

        const float p = (e < cnt) ? __expf(s * 0.25f) : 0.f;   // 1/sqrt(16)
        l_run += p;

        #pragma unroll
        for (int ee = 0; ee < 8; ++ee) {
            const float pe = __shfl(p, (lane & 0x38) | ee);    // within own head group
            acc0 = fmaf(pe, bflo(vv[ee]), acc0);
            acc1 = fmaf(pe, bfhi(vv[ee]), acc1);
        }

        // -- rotate pipeline state --
        ka = k1a; kb = k1b;
        #pragma unroll
        for (int ee = 0; ee < 8; ++ee) vv[ee] = vn[ee];
        cur = nxt; nxt = nn;
    }

    // deferred l reduction over the 8 e-lanes of each head group
    l_run += __shfl_xor(l_run, 1);
    l_run += __shfl_xor(l_run, 2);
    l_run += __shfl_xor(l_run, 4);

    const float inv = 1.f / fmaxf(l_run, 1e-30f);
    const float o0 = acc0 * inv, o1 = acc1 * inv;
    *(unsigned*)(agg + obase) = (unsigned)f2bf(o0) | ((unsigned)f2bf(o1) << 16);
}

// ---------------- launch ----------------
extern "C" void kernel_launch(void* const* d_in, const int* in_sizes, int n_in,
                              void* d_out, int out_size, void* d_ws, size_t ws_size,
                              hipStream_t stream) {
    const float* x     = (const float*)d_in[0];
    const int*   src   = (const int*)  d_in[1];
    const int*   dst   = (const int*)  d_in[2];
    const float* w_qkv = (const float*)d_in[3];
    const float* b_qkv = (const float*)d_in[4];
    const float* w_out = (const float*)d_in[5];
    const float* b_out = (const float*)d_in[6];
    float* out = (float*)d_out;

    const int N = in_sizes[0] / DD;   // 50000
    const int E = in_sizes[1];        // 800000

    typedef unsigned short u16;
    char* ws = (char*)d_ws;
    u16* qbf   = (u16*)ws;   ws += (size_t)N * DD * sizeof(u16);     // 12.8 MB
    u16* kbf   = (u16*)ws;   ws += (size_t)N * DD * sizeof(u16);     // 12.8 MB
    u16* vbf   = (u16*)ws;   ws += (size_t)N * DD * sizeof(u16);
    u16* aggb  = (u16*)ws;   ws += (size_t)N * DD * sizeof(u16);
    u16* wq_hi = (u16*)ws;   ws += (size_t)NQKV * DD * sizeof(u16);
    u16* wq_lo = (u16*)ws;   ws += (size_t)NQKV * DD * sizeof(u16);
    u16* wo_hi = (u16*)ws;   ws += (size_t)DD * DD * sizeof(u16);
    u16* wo_lo = (u16*)ws;   ws += (size_t)DD * DD * sizeof(u16);
    int* counts = (int*)ws;  ws += (size_t)((N + 3) / 4 * 4) * sizeof(int); // 200 KB
    int* lists  = (int*)ws;  ws += (size_t)N * CAP * sizeof(int);           // 25.6 MB

    const int nzc4 = (N + 3) / 4;
    const int npb  = (nzc4 + NWQ8 + NWO8 + 255) / 256;
    const int nsb  = ((E + 7) / 8 + 255) / 256;   // 8 edges/thread
    const int MB   = (N + TM - 1) / TM;

    // 1) prep: zero counters + split weights
    prep_kernel<<<npb, 256, 0, stream>>>(w_qkv, w_out, wq_hi, wq_lo, wo_hi, wo_lo,
                                         counts, nzc4);
    // 2) one-pass grouped edge-list build (8 edges/thread, atomic ILP)
    scatter_fixed_kernel<<<nsb, 256, 0, stream>>>(src, dst, counts, lists, E);

    // 3) QKV projection (n-tiles fastest for x reuse; q/k/v all bf16)
    qkv_gemm_kernel<<<dim3(NQKV / TN, MB), 256, 0, stream>>>(
        x, wq_hi, wq_lo, b_qkv, qbf, kbf, vbf, N);

    // 4) wave-per-node attention (software-pipelined; emits agg as bf16)
    wave_attn_kernel<<<(N + 3) / 4, 256, 0, stream>>>(
        qbf, kbf, vbf, lists, counts, aggb, N);

    // 5) output projection (2-pass split-bf16 weights)
    out_gemm_kernel<<<MB, 256, 0, stream>>>(
        aggb, wo_hi, wo_lo, b_out, out, N);
}